// Round 3
// baseline (585.549 us; speedup 1.0000x reference)
//
#include <hip/hip_runtime.h>
#include <stdint.h>

#define N_ROWS 8192
#define D_DIM  1024
#define BK     64

typedef __attribute__((ext_vector_type(8))) __bf16 bf16x8;
typedef __attribute__((ext_vector_type(8))) short  short8;
typedef __attribute__((ext_vector_type(4))) float  f32x4;

#define GLD16(gptr, lptr) __builtin_amdgcn_global_load_lds( \
    (const __attribute__((address_space(1))) void*)(gptr),  \
    (__attribute__((address_space(3))) void*)(lptr), 16, 0, 0)

__device__ __forceinline__ unsigned short f2bf(float v) {
    unsigned int u = __float_as_uint(v);
    u += 0x7fffu + ((u >> 16) & 1u);   // RNE
    return (unsigned short)(u >> 16);
}

// Fused: fp32->bf16 convert for both inputs (img scaled by logit_scale*log2e)
// + zero-init of row_sum/col_sum/dsum/counter in the tail blocks.
__global__ void convert_zero_kernel(const float* __restrict__ img,
                                    const float* __restrict__ txt,
                                    const float* __restrict__ scale_p,
                                    short* __restrict__ imgbf, short* __restrict__ txtbf,
                                    float* __restrict__ rs_base) {
    const int b = blockIdx.x;
    if (b >= 8192) {              // 64 zero-init blocks
        const int idx = (b - 8192) * 256 + threadIdx.x;
        rs_base[idx] = 0.f;       // row_sum[0..8191] then col_sum[0..8191]
        if (idx < 2) ((int*)(rs_base + 2 * N_ROWS))[idx] = 0;  // dsum, counter
        return;
    }
    const bool is_img = b < 4096;
    const float f     = is_img ? scale_p[0] * 1.44269504088896340736f : 1.0f;
    const float* src  = is_img ? img : txt;
    short* dst        = is_img ? imgbf : txtbf;
    const size_t idx  = ((size_t)(is_img ? b : b - 4096) * 256 + threadIdx.x) * 8;
    float4 x0 = *(const float4*)(src + idx);
    float4 x1 = *(const float4*)(src + idx + 4);
    short8 o;
    o[0] = (short)f2bf(x0.x * f); o[1] = (short)f2bf(x0.y * f);
    o[2] = (short)f2bf(x0.z * f); o[3] = (short)f2bf(x0.w * f);
    o[4] = (short)f2bf(x1.x * f); o[5] = (short)f2bf(x1.y * f);
    o[6] = (short)f2bf(x1.z * f); o[7] = (short)f2bf(x1.w * f);
    *(short8*)(dst + idx) = o;
}

// 128x128 bf16 MFMA GEMM (the verified 162us / 0-conflict structure).
// Epilogue: diagonal-logit sum (diag blocks), exp2, row/col sum atomics,
// then last-block ticket does the final loss reduction in-kernel.
__global__ void gemm_exp_kernel(const short* __restrict__ A,   // img bf16, scaled
                                const short* __restrict__ B,   // txt bf16
                                float* __restrict__ row_sum,
                                float* __restrict__ col_sum,
                                float* __restrict__ dsum,      // scalar: sum of diag logits (ln units)
                                int*   __restrict__ counter,
                                float* __restrict__ out) {
    __shared__ __align__(16) short As[128 * BK];
    __shared__ __align__(16) short Bs[128 * BK];

    const int tid  = threadIdx.x;
    const int lane = tid & 63;
    const int w    = tid >> 6;      // wave 0..3
    const int wr   = w >> 1;
    const int wc   = w & 1;
    const int ti   = blockIdx.y * 128;
    const int tj   = blockIdx.x * 128;

    const int quad = lane >> 4;
    const int l15  = lane & 15;

    const int srow = lane >> 3;               // 0..7
    const int sg   = (lane & 7) ^ srow;       // XOR-swizzled 16B k-chunk

    f32x4 acc[4][4];
#pragma unroll
    for (int i = 0; i < 4; i++)
#pragma unroll
        for (int j = 0; j < 4; j++) acc[i][j] = (f32x4){0.f, 0.f, 0.f, 0.f};

    const int arow = wr * 64 + l15;
    const int brow = wc * 64 + l15;

    for (int k0 = 0; k0 < D_DIM; k0 += BK) {
#pragma unroll
        for (int c = 0; c < 4; c++) {
            const int ch = w * 4 + c;             // wave-uniform
            const int r  = ch * 8 + srow;
            GLD16(A + (size_t)(ti + r) * D_DIM + k0 + sg * 8, As + ch * 512);
            GLD16(B + (size_t)(tj + r) * D_DIM + k0 + sg * 8, Bs + ch * 512);
        }
        __syncthreads();
#pragma unroll
        for (int kk = 0; kk < 2; kk++) {
            bf16x8 af[4], bfb[4];
#pragma unroll
            for (int fr = 0; fr < 4; fr++) {
                const int row = arow + fr * 16;
                const int kc  = ((kk << 2) + quad) ^ (row & 7);
                af[fr] = *(const bf16x8*)(As + row * BK + kc * 8);
            }
#pragma unroll
            for (int fc = 0; fc < 4; fc++) {
                const int row = brow + fc * 16;
                const int kc  = ((kk << 2) + quad) ^ (row & 7);
                bfb[fc] = *(const bf16x8*)(Bs + row * BK + kc * 8);
            }
#pragma unroll
            for (int fr = 0; fr < 4; fr++)
#pragma unroll
                for (int fc = 0; fc < 4; fc++)
                    acc[fr][fc] = __builtin_amdgcn_mfma_f32_16x16x32_bf16(
                        af[fr], bfb[fc], acc[fr][fc], 0, 0, 0);
        }
        __syncthreads();
    }

    // ---- diag: sum of l_ii (acc is logit*log2e; convert with ln2) ----
    if (blockIdx.x == blockIdx.y && wr == wc) {
        float dloc = 0.f;
#pragma unroll
        for (int fr = 0; fr < 4; fr++)
#pragma unroll
            for (int r = 0; r < 4; r++)
                if (l15 == quad * 4 + r) dloc += acc[fr][fr][r];
#pragma unroll
        for (int m = 1; m < 64; m <<= 1) dloc += __shfl_xor(dloc, m);
        if (lane == 0) atomicAdd(dsum, dloc * 0.69314718055994530942f);
    }

    // ---- exp2 ----
#pragma unroll
    for (int fr = 0; fr < 4; fr++)
#pragma unroll
        for (int fc = 0; fc < 4; fc++)
#pragma unroll
            for (int r = 0; r < 4; r++)
                acc[fr][fc][r] = __builtin_amdgcn_exp2f(acc[fr][fc][r]);

    // row sums: elem (fr,fc,r) = exp(logits[ti+wr*64+fr*16+quad*4+r][tj+wc*64+fc*16+l15])
    const int rowbase = ti + wr * 64;
#pragma unroll
    for (int fr = 0; fr < 4; fr++) {
#pragma unroll
        for (int r = 0; r < 4; r++) {
            float s = acc[fr][0][r] + acc[fr][1][r] + acc[fr][2][r] + acc[fr][3][r];
            s += __shfl_xor(s, 1);
            s += __shfl_xor(s, 2);
            s += __shfl_xor(s, 4);
            s += __shfl_xor(s, 8);
            if (l15 == 0)
                atomicAdd(&row_sum[rowbase + fr * 16 + quad * 4 + r], s);
        }
    }

    // col sums
    const int colbase = tj + wc * 64;
#pragma unroll
    for (int fc = 0; fc < 4; fc++) {
        float s = 0.f;
#pragma unroll
        for (int fr = 0; fr < 4; fr++)
#pragma unroll
            for (int r = 0; r < 4; r++) s += acc[fr][fc][r];
        s += __shfl_xor(s, 16);
        s += __shfl_xor(s, 32);
        if (quad == 0)
            atomicAdd(&col_sum[colbase + fc * 16 + l15], s);
    }

    // ---- last-block finish (all cross-block data was atomicAdd-written) ----
    __threadfence();
    __shared__ int is_last;
    if (tid == 0) is_last = (atomicAdd(counter, 1) == (64 * 64 - 1)) ? 1 : 0;
    __syncthreads();
    if (is_last) {
        float s = 0.f;
        for (int i = tid; i < N_ROWS; i += 256)
            s += __logf(row_sum[i]) + __logf(col_sum[i]);
#pragma unroll
        for (int m = 1; m < 64; m <<= 1) s += __shfl_xor(s, m);
        __shared__ float wsum[4];
        if (lane == 0) wsum[w] = s;
        __syncthreads();
        if (tid == 0) {
            float t = wsum[0] + wsum[1] + wsum[2] + wsum[3];
            out[0] = (t - 2.0f * (*dsum)) * (0.5f / (float)N_ROWS);
        }
    }
}

extern "C" void kernel_launch(void* const* d_in, const int* in_sizes, int n_in,
                              void* d_out, int out_size, void* d_ws, size_t ws_size,
                              hipStream_t stream) {
    const float* img     = (const float*)d_in[0];
    const float* txt     = (const float*)d_in[1];
    const float* scale_p = (const float*)d_in[2];
    float* out = (float*)d_out;

    char* ws = (char*)d_ws;
    short* imgbf   = (short*)ws;                                  // 16 MB
    short* txtbf   = (short*)(ws + (size_t)16 * 1024 * 1024);     // 16 MB
    float* row_sum = (float*)(ws + (size_t)32 * 1024 * 1024);     // 32 KB
    float* col_sum = row_sum + N_ROWS;                            // 32 KB
    float* dsum    = row_sum + 2 * N_ROWS;
    int*   counter = (int*)(row_sum + 2 * N_ROWS) + 1;

    convert_zero_kernel<<<8192 + 64, 256, 0, stream>>>(img, txt, scale_p,
                                                       imgbf, txtbf, row_sum);

    dim3 grid(N_ROWS / 128, N_ROWS / 128);
    gemm_exp_kernel<<<grid, 256, 0, stream>>>(imgbf, txtbf, row_sum, col_sum,
                                              dsum, counter, out);
}

// Round 4
// 275.348 us; speedup vs baseline: 2.1266x; 2.1266x over previous
//
#include <hip/hip_runtime.h>
#include <stdint.h>

#define N_ROWS 8192
#define D_DIM  1024
#define BK     64

typedef __attribute__((ext_vector_type(8))) __bf16 bf16x8;
typedef __attribute__((ext_vector_type(8))) short  short8;
typedef __attribute__((ext_vector_type(4))) float  f32x4;

#define GLD16(gptr, lptr) __builtin_amdgcn_global_load_lds( \
    (const __attribute__((address_space(1))) void*)(gptr),  \
    (__attribute__((address_space(3))) void*)(lptr), 16, 0, 0)

__device__ __forceinline__ unsigned short f2bf(float v) {
    unsigned int u = __float_as_uint(v);
    u += 0x7fffu + ((u >> 16) & 1u);   // RNE
    return (unsigned short)(u >> 16);
}

// Fused: fp32->bf16 convert for both inputs (img scaled by logit_scale*log2e)
// + zero-init of row_sum/col_sum/dsum/counter in the tail blocks.
__global__ void convert_zero_kernel(const float* __restrict__ img,
                                    const float* __restrict__ txt,
                                    const float* __restrict__ scale_p,
                                    short* __restrict__ imgbf, short* __restrict__ txtbf,
                                    float* __restrict__ rs_base) {
    const int b = blockIdx.x;
    if (b >= 8192) {              // 64 zero-init blocks
        const int idx = (b - 8192) * 256 + threadIdx.x;
        rs_base[idx] = 0.f;       // row_sum[0..8191] then col_sum[0..8191]
        if (idx < 2) ((int*)(rs_base + 2 * N_ROWS))[idx] = 0;  // dsum, counter
        return;
    }
    const bool is_img = b < 4096;
    const float f     = is_img ? scale_p[0] * 1.44269504088896340736f : 1.0f;
    const float* src  = is_img ? img : txt;
    short* dst        = is_img ? imgbf : txtbf;
    const size_t idx  = ((size_t)(is_img ? b : b - 4096) * 256 + threadIdx.x) * 8;
    float4 x0 = *(const float4*)(src + idx);
    float4 x1 = *(const float4*)(src + idx + 4);
    short8 o;
    o[0] = (short)f2bf(x0.x * f); o[1] = (short)f2bf(x0.y * f);
    o[2] = (short)f2bf(x0.z * f); o[3] = (short)f2bf(x0.w * f);
    o[4] = (short)f2bf(x1.x * f); o[5] = (short)f2bf(x1.y * f);
    o[6] = (short)f2bf(x1.z * f); o[7] = (short)f2bf(x1.w * f);
    *(short8*)(dst + idx) = o;
}

// 128x128 bf16 MFMA GEMM (verified 162us / 0-conflict structure).
// Epilogue: diag-logit sum (diag blocks), exp2, row/col sum atomics, then
// last-block ticket finish. NO agent-scope fence (buffer_wbl2/inv storm was
// the R3 3x regression) — workgroup release fence (s_waitcnt vmcnt(0)) is
// sufficient because all cross-block data moves via device-scope atomics.
__global__ void gemm_exp_kernel(const short* __restrict__ A,   // img bf16, scaled
                                const short* __restrict__ B,   // txt bf16
                                float* __restrict__ row_sum,
                                float* __restrict__ col_sum,
                                float* __restrict__ dsum,      // scalar: sum diag logits (ln units)
                                int*   __restrict__ counter,
                                float* __restrict__ out) {
    __shared__ __align__(16) short As[128 * BK];
    __shared__ __align__(16) short Bs[128 * BK];

    const int tid  = threadIdx.x;
    const int lane = tid & 63;
    const int w    = tid >> 6;      // wave 0..3
    const int wr   = w >> 1;
    const int wc   = w & 1;
    const int ti   = blockIdx.y * 128;
    const int tj   = blockIdx.x * 128;

    const int quad = lane >> 4;
    const int l15  = lane & 15;

    const int srow = lane >> 3;               // 0..7
    const int sg   = (lane & 7) ^ srow;       // XOR-swizzled 16B k-chunk

    f32x4 acc[4][4];
#pragma unroll
    for (int i = 0; i < 4; i++)
#pragma unroll
        for (int j = 0; j < 4; j++) acc[i][j] = (f32x4){0.f, 0.f, 0.f, 0.f};

    const int arow = wr * 64 + l15;
    const int brow = wc * 64 + l15;

    for (int k0 = 0; k0 < D_DIM; k0 += BK) {
#pragma unroll
        for (int c = 0; c < 4; c++) {
            const int ch = w * 4 + c;             // wave-uniform
            const int r  = ch * 8 + srow;
            GLD16(A + (size_t)(ti + r) * D_DIM + k0 + sg * 8, As + ch * 512);
            GLD16(B + (size_t)(tj + r) * D_DIM + k0 + sg * 8, Bs + ch * 512);
        }
        __syncthreads();
#pragma unroll
        for (int kk = 0; kk < 2; kk++) {
            bf16x8 af[4], bfb[4];
#pragma unroll
            for (int fr = 0; fr < 4; fr++) {
                const int row = arow + fr * 16;
                const int kc  = ((kk << 2) + quad) ^ (row & 7);
                af[fr] = *(const bf16x8*)(As + row * BK + kc * 8);
            }
#pragma unroll
            for (int fc = 0; fc < 4; fc++) {
                const int row = brow + fc * 16;
                const int kc  = ((kk << 2) + quad) ^ (row & 7);
                bfb[fc] = *(const bf16x8*)(Bs + row * BK + kc * 8);
            }
#pragma unroll
            for (int fr = 0; fr < 4; fr++)
#pragma unroll
                for (int fc = 0; fc < 4; fc++)
                    acc[fr][fc] = __builtin_amdgcn_mfma_f32_16x16x32_bf16(
                        af[fr], bfb[fc], acc[fr][fc], 0, 0, 0);
        }
        __syncthreads();
    }

    // ---- diag: sum of l_ii (acc is logit*log2e; convert with ln2) ----
    if (blockIdx.x == blockIdx.y && wr == wc) {
        float dloc = 0.f;
#pragma unroll
        for (int fr = 0; fr < 4; fr++)
#pragma unroll
            for (int r = 0; r < 4; r++)
                if (l15 == quad * 4 + r) dloc += acc[fr][fr][r];
#pragma unroll
        for (int m = 1; m < 64; m <<= 1) dloc += __shfl_xor(dloc, m);
        if (lane == 0) atomicAdd(dsum, dloc * 0.69314718055994530942f);
    }

    // ---- exp2 ----
#pragma unroll
    for (int fr = 0; fr < 4; fr++)
#pragma unroll
        for (int fc = 0; fc < 4; fc++)
#pragma unroll
            for (int r = 0; r < 4; r++)
                acc[fr][fc][r] = __builtin_amdgcn_exp2f(acc[fr][fc][r]);

    // row sums
    const int rowbase = ti + wr * 64;
#pragma unroll
    for (int fr = 0; fr < 4; fr++) {
#pragma unroll
        for (int r = 0; r < 4; r++) {
            float s = acc[fr][0][r] + acc[fr][1][r] + acc[fr][2][r] + acc[fr][3][r];
            s += __shfl_xor(s, 1);
            s += __shfl_xor(s, 2);
            s += __shfl_xor(s, 4);
            s += __shfl_xor(s, 8);
            if (l15 == 0)
                atomicAdd(&row_sum[rowbase + fr * 16 + quad * 4 + r], s);
        }
    }

    // col sums
    const int colbase = tj + wc * 64;
#pragma unroll
    for (int fc = 0; fc < 4; fc++) {
        float s = 0.f;
#pragma unroll
        for (int fr = 0; fr < 4; fr++)
#pragma unroll
            for (int r = 0; r < 4; r++) s += acc[fr][fc][r];
        s += __shfl_xor(s, 16);
        s += __shfl_xor(s, 32);
        if (quad == 0)
            atomicAdd(&col_sum[colbase + fc * 16 + l15], s);
    }

    // ---- last-block finish ----
    // Workgroup-scope release: s_waitcnt vmcnt(0) only — guarantees this
    // block's device-scope atomics committed at the coherence point. No L2
    // writeback/invalidate (that was the R3 regression).
    __builtin_amdgcn_fence(__ATOMIC_RELEASE, "workgroup");
    int* sh_flag  = (int*)Bs;     // reuse LDS (keep LDS_Block_Size at 32768)
    float* sh_sum = (float*)As;
    if (tid == 0) sh_flag[0] = (atomicAdd(counter, 1) == (64 * 64 - 1)) ? 1 : 0;
    __syncthreads();
    if (sh_flag[0]) {
        float s = 0.f;
        for (int i = tid; i < N_ROWS; i += 256) {
            float r = __hip_atomic_load(&row_sum[i], __ATOMIC_RELAXED,
                                        __HIP_MEMORY_SCOPE_AGENT);
            float c = __hip_atomic_load(&col_sum[i], __ATOMIC_RELAXED,
                                        __HIP_MEMORY_SCOPE_AGENT);
            s += __logf(r) + __logf(c);
        }
#pragma unroll
        for (int m = 1; m < 64; m <<= 1) s += __shfl_xor(s, m);
        if (lane == 0) sh_sum[w] = s;
        __syncthreads();
        if (tid == 0) {
            float d = __hip_atomic_load(dsum, __ATOMIC_RELAXED,
                                        __HIP_MEMORY_SCOPE_AGENT);
            float t = sh_sum[0] + sh_sum[1] + sh_sum[2] + sh_sum[3];
            out[0] = (t - 2.0f * d) * (0.5f / (float)N_ROWS);
        }
    }
}

extern "C" void kernel_launch(void* const* d_in, const int* in_sizes, int n_in,
                              void* d_out, int out_size, void* d_ws, size_t ws_size,
                              hipStream_t stream) {
    const float* img     = (const float*)d_in[0];
    const float* txt     = (const float*)d_in[1];
    const float* scale_p = (const float*)d_in[2];
    float* out = (float*)d_out;

    char* ws = (char*)d_ws;
    short* imgbf   = (short*)ws;                                  // 16 MB
    short* txtbf   = (short*)(ws + (size_t)16 * 1024 * 1024);     // 16 MB
    float* row_sum = (float*)(ws + (size_t)32 * 1024 * 1024);     // 32 KB
    float* col_sum = row_sum + N_ROWS;                            // 32 KB
    float* dsum    = row_sum + 2 * N_ROWS;
    int*   counter = (int*)(row_sum + 2 * N_ROWS) + 1;

    convert_zero_kernel<<<8192 + 64, 256, 0, stream>>>(img, txt, scale_p,
                                                       imgbf, txtbf, row_sum);

    dim3 grid(N_ROWS / 128, N_ROWS / 128);
    gemm_exp_kernel<<<grid, 256, 0, stream>>>(imgbf, txtbf, row_sum, col_sum,
                                              dsum, counter, out);
}